// Round 7
// baseline (356.734 us; speedup 1.0000x reference)
//
#include <hip/hip_runtime.h>
#include <hip/hip_bf16.h>

typedef unsigned short u16;
typedef __attribute__((ext_vector_type(8))) short bf16x8;
typedef __attribute__((ext_vector_type(4))) float f32x4;

#define BTOK 4096
#define DDIM 1024
#define NEXP 8
#define HDIM 4096
#define ODIM 1024
#define MAXTILES 40
#define MAXROWS (MAXTILES * 128)  // 5120

__device__ __forceinline__ u16 f2bf(float f) {
  unsigned u = __float_as_uint(f);
  return (u16)((u + 0x7FFFu + ((u >> 16) & 1u)) >> 16);  // RNE
}
__device__ __forceinline__ u16 cvt_bf(float f) {  // HW cvt, RNE
  __hip_bfloat16 h = __float2bfloat16(f);
  u16 r;
  __builtin_memcpy(&r, &h, 2);
  return r;
}

__device__ __forceinline__ void gload16(const void* g, void* l) {
  __builtin_amdgcn_global_load_lds(
      (const __attribute__((address_space(1))) void*)g,
      (__attribute__((address_space(3))) void*)l, 16, 0, 0);
}

// ---------------- init: clear control block + rowmap ----------------
__global__ __launch_bounds__(256) void init_kernel(int* __restrict__ ctrl,
                                                   int* __restrict__ rowmap) {
  int i = blockIdx.x * 256 + threadIdx.x;
  if (i < 1024)
    ctrl[i] = 0;
  else
    rowmap[i - 1024] = -1;  // 5120 entries
}

// ---------------- gating: one wave per token, fp64 accumulate ----------------
__global__ __launch_bounds__(256) void gate_kernel(
    const float* __restrict__ x, const float* __restrict__ Wg,
    const float* __restrict__ bg, int* __restrict__ assign,
    int* __restrict__ counts) {
  int wave = threadIdx.x >> 6;
  int lane = threadIdx.x & 63;
  int b = blockIdx.x * 4 + wave;
  const float* xr = x + (size_t)b * DDIM;
  double acc[NEXP];
#pragma unroll
  for (int e = 0; e < NEXP; ++e) acc[e] = 0.0;
  for (int d = lane; d < DDIM; d += 64) {
    float xv = xr[d];
    const float4* wrow = (const float4*)(Wg + d * NEXP);
    float4 w0 = wrow[0], w1 = wrow[1];
    acc[0] += (double)xv * (double)w0.x;
    acc[1] += (double)xv * (double)w0.y;
    acc[2] += (double)xv * (double)w0.z;
    acc[3] += (double)xv * (double)w0.w;
    acc[4] += (double)xv * (double)w1.x;
    acc[5] += (double)xv * (double)w1.y;
    acc[6] += (double)xv * (double)w1.z;
    acc[7] += (double)xv * (double)w1.w;
  }
#pragma unroll
  for (int e = 0; e < NEXP; ++e) {
    double v = acc[e];
#pragma unroll
    for (int off = 32; off > 0; off >>= 1) v += __shfl_xor(v, off);
    acc[e] = v;
  }
  if (lane == 0) {
    int best = 0;
    double bv = acc[0] + (double)bg[0];
#pragma unroll
    for (int e = 1; e < NEXP; ++e) {
      double v = acc[e] + (double)bg[e];
      if (v > bv) { bv = v; best = e; }  // first max wins (matches jnp.argmax)
    }
    assign[b] = best;
    atomicAdd(&counts[best], 1);
  }
}

// ---------------- setup: offsets, tile table, balance loss ----------------
__global__ void setup_kernel(const int* __restrict__ counts,
                             const float* __restrict__ wbal,
                             int* __restrict__ offp, int* __restrict__ tile_e,
                             int* __restrict__ tile_m, int* __restrict__ meta,
                             float* __restrict__ loss_out) {
  if (threadIdx.x != 0 || blockIdx.x != 0) return;
  int off = 0, nt = 0;
  for (int e = 0; e < NEXP; ++e) {
    offp[e] = off;
    int pc = (counts[e] + 127) & ~127;  // pad to 128
    for (int t = 0; t < (pc >> 7); ++t) {
      tile_e[nt] = e;
      tile_m[nt] = off + t * 128;
      ++nt;
    }
    off += pc;
  }
  offp[NEXP] = off;
  meta[0] = nt;
  float mean = (float)BTOK / (float)NEXP;
  float s = 0.f;
  for (int e = 0; e < NEXP; ++e) {
    float d = (float)counts[e] - mean;
    s += d * d;
  }
  loss_out[0] = s / (float)NEXP * wbal[0];
}

// -------- transpose chunk: fp32 [K][N] -> bf16 [N][K], 64k x 256n per block --
// chunk: e = c>>8, r = c&255; kc = r % (K/64), nc = r / (K/64).
__device__ __forceinline__ void transpose_chunk(const float* __restrict__ W,
                                                u16* __restrict__ wt, int K,
                                                int N, int chunk,
                                                float (*lds)[68]) {
  const int t = threadIdx.x;
  const int e = chunk >> 8;
  const int r = chunk & 255;
  const int nK = K >> 6;
  const int kb = (r & (nK - 1)) * 64;
  const int nb0 = (r / nK) * 256;
  const float* src = W + (size_t)e * K * N;
  const int rr = t >> 4, cc = (t & 15) * 4;
  const int n = t & 63, kg = (t >> 6) * 16;
#pragma unroll 1
  for (int s = 0; s < 4; ++s) {
    const int nb = nb0 + s * 64;
#pragma unroll
    for (int p = 0; p < 4; ++p) {
      float4 v =
          *(const float4*)(src + (size_t)(kb + rr + p * 16) * N + nb + cc);
      *(float4*)&lds[rr + p * 16][cc] = v;
    }
    __syncthreads();
    alignas(16) u16 tmp[16];
#pragma unroll
    for (int i = 0; i < 16; ++i) tmp[i] = cvt_bf(lds[kg + i][n]);
    u16* dst = wt + ((size_t)e * N + nb + n) * K + kb + kg;
    *(float4*)dst = *(float4*)&tmp[0];
    *(float4*)(dst + 8) = *(float4*)&tmp[8];
    __syncthreads();
  }
}

// ---------------- fusedA: gather tokens (blocks 0..4095) + transpose W1 ------
__global__ __launch_bounds__(256, 4) void fused_gather_t1(
    const float* __restrict__ x, const int* __restrict__ assign,
    const int* __restrict__ offp, int* __restrict__ fill,
    int* __restrict__ rowmap, u16* __restrict__ xg,
    const float* __restrict__ W1, u16* __restrict__ wt1) {
  __shared__ __align__(16) float tl[64][68];
  const int id = blockIdx.x;
  if (id < BTOK) {
    __shared__ int srow;
    if (threadIdx.x == 0) {
      int e = assign[id];
      int pos = atomicAdd(&fill[e], 1);
      int row = offp[e] + pos;
      rowmap[row] = id;
      srow = row;
    }
    __syncthreads();
    int row = srow;
    float4 v = *(const float4*)(x + (size_t)id * DDIM + threadIdx.x * 4);
    ushort4 o;
    o.x = f2bf(v.x);
    o.y = f2bf(v.y);
    o.z = f2bf(v.z);
    o.w = f2bf(v.w);
    *(ushort4*)(xg + (size_t)row * DDIM + threadIdx.x * 4) = o;
  } else {
    transpose_chunk(W1, wt1, DDIM, HDIM, id - BTOK, tl);
  }
}

// ---------------- GEMM core: 128x128 tile, BK=32, counted-vmcnt pipeline -----
// Both operands bf16 K-contig. All staging via global_load_lds (4/step) into
// double-buffered swizzled LDS: unit(r,kq) = r*4 + (kq ^ ((r>>1)&3)) -> b128
// reads 2-way bank-aliased (free). Pipeline: stage(t+1) issued, then inline
// vmcnt(4) waits only for stage(t)'s loads (t+1's 4 stay in flight across the
// barrier, T4), sched_barrier fences stop reordering, setprio(1) on MFMA (T5).
// MODE 0: Hout = relu(acc + bias) bf16;  MODE 1: P[z] = acc (fp32 partials)
template <int MODE>
__device__ __forceinline__ void gemm_core(
    u16* lds, int bx, int by, int bz, const u16* __restrict__ A, int lda,
    const u16* __restrict__ BT, int ldb, int nbRows,
    const float* __restrict__ bias, const int* __restrict__ tile_e,
    const int* __restrict__ tile_m, u16* __restrict__ Hout, int ldn,
    float* __restrict__ P, size_t pStride, int nkt) {
  const int e = tile_e[bx];
  const int m0 = tile_m[bx];
  const int n0 = by * 128;
  const int kOff = bz * nkt * 32;

  const int tid = threadIdx.x;
  const int lane = tid & 63;
  const int wave = tid >> 6;
  const int wr = wave >> 1, wc = wave & 1;
  const int fr = lane & 15;
  const int kqr = lane >> 4;

  // staging source (inverse swizzle), units tid and tid+256
  const int r0 = tid >> 2, k0 = (tid & 3) ^ ((r0 >> 1) & 3);
  const int r1 = (tid + 256) >> 2, k1 = ((tid + 256) & 3) ^ ((r1 >> 1) & 3);
  const u16* aS0 = A + (size_t)(m0 + r0) * lda + kOff + k0 * 8;
  const u16* aS1 = A + (size_t)(m0 + r1) * lda + kOff + k1 * 8;
  const u16* bPan = BT + ((size_t)e * nbRows + n0) * ldb + kOff;
  const u16* bS0 = bPan + (size_t)r0 * ldb + k0 * 8;
  const u16* bS1 = bPan + (size_t)r1 * ldb + k1 * 8;
  const int dst0 = (tid & ~63) * 8;  // u16 units, lane-linear per wave
  const int dst1 = dst0 + 2048;

  // fragment offsets (u16 units, swizzled)
  int aOff[4], bOff[4];
#pragma unroll
  for (int i = 0; i < 4; ++i) {
    int r = wr * 64 + i * 16 + fr;
    aOff[i] = (r * 4 + (kqr ^ ((r >> 1) & 3))) * 8;
    int c = wc * 64 + i * 16 + fr;
    bOff[i] = (c * 4 + (kqr ^ ((c >> 1) & 3))) * 8;
  }

  f32x4 acc[4][4];
#pragma unroll
  for (int i = 0; i < 4; ++i)
#pragma unroll
    for (int j = 0; j < 4; ++j)
#pragma unroll
      for (int r = 0; r < 4; ++r) acc[i][j][r] = 0.f;

  auto stage = [&](int c, int kt) {
    const int ko = kt * 32;
    u16* base = lds + c * 8192;
    gload16(aS0 + ko, base + dst0);
    gload16(aS1 + ko, base + dst1);
    gload16(bS0 + ko, base + 4096 + dst0);
    gload16(bS1 + ko, base + 4096 + dst1);
  };
  auto compute = [&](int c) {
    const u16* base = lds + c * 8192;
    bf16x8 af[4], bfr[4];
#pragma unroll
    for (int i = 0; i < 4; ++i) {
      af[i] = *(const bf16x8*)(base + aOff[i]);
      bfr[i] = *(const bf16x8*)(base + 4096 + bOff[i]);
    }
    __builtin_amdgcn_s_setprio(1);
#pragma unroll
    for (int i = 0; i < 4; ++i)
#pragma unroll
      for (int j = 0; j < 4; ++j)
        acc[i][j] = __builtin_amdgcn_mfma_f32_16x16x32_bf16(af[i], bfr[j],
                                                            acc[i][j], 0, 0, 0);
    __builtin_amdgcn_s_setprio(0);
  };

  stage(0, 0);
  int cur = 0;
#pragma unroll 1
  for (int kt = 0; kt < nkt - 1; ++kt) {
    stage(cur ^ 1, kt + 1);  // 4 loads stay in flight across the barrier
    asm volatile("s_waitcnt vmcnt(4)" ::: "memory");  // retire stage(cur,kt)
    __builtin_amdgcn_sched_barrier(0);
    __builtin_amdgcn_s_barrier();
    __builtin_amdgcn_sched_barrier(0);
    compute(cur);
    __builtin_amdgcn_sched_barrier(0);
    __builtin_amdgcn_s_barrier();  // all reads of cur done before re-stage
    cur ^= 1;
  }
  asm volatile("s_waitcnt vmcnt(0)" ::: "memory");
  __builtin_amdgcn_sched_barrier(0);
  __builtin_amdgcn_s_barrier();
  __builtin_amdgcn_sched_barrier(0);
  compute(cur);

  // epilogue: C/D layout col = lane&15, row = (lane>>4)*4 + reg
  if constexpr (MODE == 0) {
#pragma unroll
    for (int i = 0; i < 4; ++i) {
      int rbase = m0 + wr * 64 + i * 16 + (lane >> 4) * 4;
#pragma unroll
      for (int j = 0; j < 4; ++j) {
        int col = n0 + wc * 64 + j * 16 + fr;
        float bv = bias[e * ldn + col];
#pragma unroll
        for (int r = 0; r < 4; ++r) {
          float v = acc[i][j][r] + bv;
          v = v > 0.f ? v : 0.f;
          Hout[(size_t)(rbase + r) * ldn + col] = f2bf(v);
        }
      }
    }
  } else {
    float* Pp = P + bz * pStride;
#pragma unroll
    for (int i = 0; i < 4; ++i) {
      int rbase = m0 + wr * 64 + i * 16 + (lane >> 4) * 4;
#pragma unroll
      for (int j = 0; j < 4; ++j) {
        int col = n0 + wc * 64 + j * 16 + fr;
#pragma unroll
        for (int r = 0; r < 4; ++r)
          Pp[(size_t)(rbase + r) * ODIM + col] = acc[i][j][r];
      }
    }
  }
}

// ---------------- fusedB: GEMM1 (blocks 0..1279) + transpose W2 --------------
__global__ __launch_bounds__(256, 4) void fused_g1_t2(
    const u16* __restrict__ xg, const u16* __restrict__ wt1,
    const float* __restrict__ b1, const float* __restrict__ W2,
    u16* __restrict__ wt2, u16* __restrict__ h, const int* __restrict__ tile_e,
    const int* __restrict__ tile_m, const int* __restrict__ meta) {
  __shared__ __align__(16) char smem[32768];
  const int id = blockIdx.x;
  if (id < 1280) {
    // bijective XCD swizzle over 1280 (q = 160)
    const int wg = (id & 7) * 160 + (id >> 3);
    const int bx = wg % MAXTILES, by = wg / MAXTILES;
    if (bx >= meta[0]) return;
    gemm_core<0>((u16*)smem, bx, by, 0, xg, DDIM, wt1, DDIM, HDIM, b1, tile_e,
                 tile_m, h, HDIM, nullptr, 0, DDIM / 32);
  } else {
    transpose_chunk(W2, wt2, HDIM, ODIM, id - 1280, (float(*)[68])smem);
  }
}

// ---------------- GEMM2: h @ wt2 -> P (z-split K) ----------------
__global__ __launch_bounds__(256, 4) void moe_gemm2(
    const u16* __restrict__ h, const u16* __restrict__ wt2,
    const int* __restrict__ tile_e, const int* __restrict__ tile_m,
    const int* __restrict__ meta, float* __restrict__ P, size_t pStride) {
  __shared__ __align__(16) u16 lds[2 * 8192];
  const int orig = blockIdx.y * MAXTILES + blockIdx.x;  // nwg = 320, q = 40
  const int wg = (orig & 7) * 40 + (orig >> 3);
  const int bx = wg % MAXTILES, by = wg / MAXTILES;
  if (bx >= meta[0]) return;
  gemm_core<1>(lds, bx, by, blockIdx.z, h, HDIM, wt2, HDIM, ODIM, nullptr,
               tile_e, tile_m, nullptr, 0, P, pStride, (HDIM / 2) / 32);
}

// ---------------- reduce: out[tok] = P0 + P1 + b2 ----------------
__global__ __launch_bounds__(256) void reduce_kernel(
    const float* __restrict__ P, size_t pStride, const int* __restrict__ rowmap,
    const int* __restrict__ tile_e, const int* __restrict__ tile_m,
    const int* __restrict__ meta, const float* __restrict__ b2,
    float* __restrict__ out) {
  if ((int)blockIdx.x >= meta[0]) return;
  const int e = tile_e[blockIdx.x];
  const int m0 = tile_m[blockIdx.x];
  const int c0 = blockIdx.y * 128;
#pragma unroll 1
  for (int it = 0; it < 16; ++it) {
    int idx = it * 256 + threadIdx.x;  // 4096 float4 per block
    int r = idx >> 5, cq = idx & 31;
    int row = m0 + r;
    int tok = rowmap[row];
    if (tok < 0) continue;
    int c = c0 + cq * 4;
    float4 a = *(const float4*)(P + (size_t)row * ODIM + c);
    float4 b = *(const float4*)(P + pStride + (size_t)row * ODIM + c);
    float4 bb = *(const float4*)(b2 + (size_t)e * ODIM + c);
    float4 o;
    o.x = a.x + b.x + bb.x;
    o.y = a.y + b.y + bb.y;
    o.z = a.z + b.z + bb.z;
    o.w = a.w + b.w + bb.w;
    *(float4*)(out + (size_t)tok * ODIM + c) = o;
  }
}

extern "C" void kernel_launch(void* const* d_in, const int* in_sizes, int n_in,
                              void* d_out, int out_size, void* d_ws,
                              size_t ws_size, hipStream_t stream) {
  const float* x = (const float*)d_in[0];
  const float* Wg = (const float*)d_in[1];
  const float* bg = (const float*)d_in[2];
  const float* W1 = (const float*)d_in[3];
  const float* b1 = (const float*)d_in[4];
  const float* W2 = (const float*)d_in[5];
  const float* b2 = (const float*)d_in[6];
  const float* wbal = (const float*)d_in[7];
  float* out = (float*)d_out;

  char* ws = (char*)d_ws;
  int* counts = (int*)(ws + 0);
  int* fill = (int*)(ws + 64);
  int* offp = (int*)(ws + 128);
  int* meta = (int*)(ws + 192);
  int* tile_e = (int*)(ws + 256);
  int* tile_m = (int*)(ws + 512);
  int* assign = (int*)(ws + 4096);
  int* rowmap = (int*)(ws + 20480);
  u16* xg = (u16*)(ws + 65536);           // 5120x1024 bf16      (10.5 MB)
  u16* h = (u16*)(ws + 10551296);         // 5120x4096 bf16      (41.9 MB)
  float* P = (float*)(ws + 52494336);     // 2x5120x1024 fp32    (41.9 MB)
  u16* wt1 = (u16*)(ws + 94437376);       // [8][4096][1024] bf16 (67.1 MB)
  u16* wt2 = (u16*)(ws + 161546240);      // [8][1024][4096] bf16 (67.1 MB)
  const size_t pStride = (size_t)MAXROWS * ODIM;

  init_kernel<<<24, 256, 0, stream>>>((int*)ws, rowmap);
  gate_kernel<<<BTOK / 4, 256, 0, stream>>>(x, Wg, bg, assign, counts);
  setup_kernel<<<1, 64, 0, stream>>>(counts, wbal, offp, tile_e, tile_m, meta,
                                     out + (size_t)BTOK * ODIM);
  // gather (4096 blocks) + W1 transpose (2048 blocks) co-scheduled
  fused_gather_t1<<<BTOK + 2048, 256, 0, stream>>>(x, assign, offp, fill,
                                                   rowmap, xg, W1, wt1);
  // GEMM1 (1280 blocks) + W2 transpose (2048 blocks) co-scheduled
  fused_g1_t2<<<1280 + 2048, 256, 0, stream>>>(xg, wt1, b1, W2, wt2, h, tile_e,
                                               tile_m, meta);
  // GEMM2: z-split K (2x2048), fp32 partials
  moe_gemm2<<<dim3(MAXTILES, ODIM / 128, 2), 256, 0, stream>>>(
      h, wt2, tile_e, tile_m, meta, P, pStride);
  reduce_kernel<<<dim3(MAXTILES, ODIM / 128), 256, 0, stream>>>(
      P, pStride, rowmap, tile_e, tile_m, meta, b2, out);
}